// Round 1
// baseline (5687.737 us; speedup 1.0000x reference)
//
#include <hip/hip_runtime.h>

// VGAE on GCN: N=50000 nodes, E=1.6M edges, IN=256, HIDDEN=128, OUT=64 (fp32).
// Pipeline: deg/dinv -> GEMM1 -> agg1(+bias,relu, h lives in d_out) ->
//           GEMM2 (W_mu|W_ls fused) -> agg2 (writes mu||logstd to d_out).

#define IN_DIM 256
#define F1 128   // HIDDEN
#define F2 64    // OUT

static __host__ __device__ inline int cdiv_i(int a, int b) { return (a + b - 1) / b; }

// ---- Wcat = [W_mu | W_ls] : [128, 128] ----
__global__ void k_build_wcat(const float* __restrict__ Wmu, const float* __restrict__ Wls,
                             float* __restrict__ Wcat) {
    int i = blockIdx.x * blockDim.x + threadIdx.x;
    if (i >= F1 * 2 * F2) return;
    int k = i >> 7;        // row (0..127)
    int c = i & 127;       // col (0..127)
    Wcat[i] = (c < F2) ? Wmu[k * F2 + c] : Wls[k * F2 + (c - F2)];
}

// ---- degree / dinv ----
__global__ void k_deg_init(float* __restrict__ deg, int N) {
    int i = blockIdx.x * blockDim.x + threadIdx.x;
    if (i < N) deg[i] = 1.0f;   // self-loop
}
__global__ void k_deg_count(const int* __restrict__ dst, float* __restrict__ deg, int E) {
    int e = blockIdx.x * blockDim.x + threadIdx.x;
    if (e < E) atomicAdd(&deg[dst[e]], 1.0f);
}
__global__ void k_dinv(float* __restrict__ deg, int N) {
    int i = blockIdx.x * blockDim.x + threadIdx.x;
    if (i < N) deg[i] = rsqrtf(deg[i]);   // deg >= 1 always
}

// ---- fp32 GEMM: C[M,N] = A[M,K] @ B[K,N]; BM=BN=64, BK=16, 256 thr, 4x4/thread ----
// Requires K % 16 == 0, N % 64 == 0 (K in {256,128}, N = 128 here). M bounds-checked.
__global__ __launch_bounds__(256) void k_gemm(const float* __restrict__ A,
                                              const float* __restrict__ B,
                                              float* __restrict__ C,
                                              int M, int K, int N) {
    __shared__ float As[16][64];   // As[k][m]
    __shared__ float Bs[16][64];   // Bs[k][n]
    const int bm = blockIdx.x * 64;
    const int bn = blockIdx.y * 64;
    const int tid = threadIdx.x;
    const int tm = (tid >> 4) << 2;   // 0..60
    const int tn = (tid & 15) << 2;   // 0..60
    const int ar = tid >> 2;              // A tile row 0..63
    const int ac = (tid & 3) << 2;        // A tile k-offset 0,4,8,12
    const int br = tid >> 4;              // B tile k-row 0..15
    const int bc = (tid & 15) << 2;       // B tile col offset

    float acc[4][4] = {{0.f}};

    for (int k0 = 0; k0 < K; k0 += 16) {
        float4 av = make_float4(0.f, 0.f, 0.f, 0.f);
        if (bm + ar < M) av = *(const float4*)(A + (size_t)(bm + ar) * K + k0 + ac);
        As[ac + 0][ar] = av.x; As[ac + 1][ar] = av.y;
        As[ac + 2][ar] = av.z; As[ac + 3][ar] = av.w;
        *(float4*)&Bs[br][bc] = *(const float4*)(B + (size_t)(k0 + br) * N + bn + bc);
        __syncthreads();
#pragma unroll
        for (int k = 0; k < 16; ++k) {
            float4 a = *(const float4*)&As[k][tm];
            float4 b = *(const float4*)&Bs[k][tn];
            acc[0][0] += a.x * b.x; acc[0][1] += a.x * b.y; acc[0][2] += a.x * b.z; acc[0][3] += a.x * b.w;
            acc[1][0] += a.y * b.x; acc[1][1] += a.y * b.y; acc[1][2] += a.y * b.z; acc[1][3] += a.y * b.w;
            acc[2][0] += a.z * b.x; acc[2][1] += a.z * b.y; acc[2][2] += a.z * b.z; acc[2][3] += a.z * b.w;
            acc[3][0] += a.w * b.x; acc[3][1] += a.w * b.y; acc[3][2] += a.w * b.z; acc[3][3] += a.w * b.w;
        }
        __syncthreads();
    }
#pragma unroll
    for (int i = 0; i < 4; ++i) {
        int gr = bm + tm + i;
        if (gr < M)
            *(float4*)(C + (size_t)gr * N + bn + tn) =
                make_float4(acc[i][0], acc[i][1], acc[i][2], acc[i][3]);
    }
}

// ---- agg1 init: h[n,c] = t[n,c]*dinv[n]^2 + b1[c]   (h has stride 128) ----
__global__ void k_agg_init_h(const float* __restrict__ t, const float* __restrict__ dinv,
                             const float* __restrict__ b1, float* __restrict__ h, int N) {
    int i = blockIdx.x * blockDim.x + threadIdx.x;
    int n = i >> 7, c = i & 127;
    if (n >= N) return;
    float di = dinv[n];
    h[i] = t[i] * di * di + b1[c];
}

// ---- agg1 edges: h[dst] += t[src] * dinv[src]*dinv[dst]  (128 feats, 32 lanes/edge) ----
__global__ void k_agg_edges128(const int* __restrict__ src, const int* __restrict__ dst,
                               const float* __restrict__ dinv, const float* __restrict__ t,
                               float* __restrict__ h, int E) {
    int g = blockIdx.x * blockDim.x + threadIdx.x;
    int e = g >> 5, lane = g & 31;
    if (e >= E) return;
    int s = src[e], d = dst[e];
    float w = dinv[s] * dinv[d];
    float4 v = *(const float4*)(t + (size_t)s * 128 + (lane << 2));
    float* o = h + (size_t)d * 128 + (lane << 2);
    atomicAdd(o + 0, v.x * w);
    atomicAdd(o + 1, v.y * w);
    atomicAdd(o + 2, v.z * w);
    atomicAdd(o + 3, v.w * w);
}

__global__ void k_relu(float* __restrict__ h, int n) {
    int i = blockIdx.x * blockDim.x + threadIdx.x;
    if (i < n) h[i] = fmaxf(h[i], 0.f);
}

// ---- agg2 init: out(mu||ls) = t2*dinv^2 + bias, split into the two output halves ----
__global__ void k_agg_init_out(const float* __restrict__ t2, const float* __restrict__ dinv,
                               const float* __restrict__ bmu, const float* __restrict__ bls,
                               float* __restrict__ out, int N) {
    int i = blockIdx.x * blockDim.x + threadIdx.x;   // over N*128
    int n = i >> 7, c = i & 127;
    if (n >= N) return;
    float di = dinv[n];
    float v = t2[i] * di * di;
    if (c < F2) out[(size_t)n * F2 + c] = v + bmu[c];
    else        out[(size_t)N * F2 + (size_t)n * F2 + (c - F2)] = v + bls[c - F2];
}

// ---- agg2 edges: scatter t2[src]*norm into mu/logstd halves of d_out ----
__global__ void k_agg_edges_out(const int* __restrict__ src, const int* __restrict__ dst,
                                const float* __restrict__ dinv, const float* __restrict__ t2,
                                float* __restrict__ out, int N, int E) {
    int g = blockIdx.x * blockDim.x + threadIdx.x;
    int e = g >> 5, lane = g & 31;
    if (e >= E) return;
    int s = src[e], d = dst[e];
    float w = dinv[s] * dinv[d];
    float4 v = *(const float4*)(t2 + (size_t)s * 128 + (lane << 2));
    float* o;
    if (lane < 16) o = out + (size_t)d * F2 + (lane << 2);
    else           o = out + (size_t)N * F2 + (size_t)d * F2 + ((lane - 16) << 2);
    atomicAdd(o + 0, v.x * w);
    atomicAdd(o + 1, v.y * w);
    atomicAdd(o + 2, v.z * w);
    atomicAdd(o + 3, v.w * w);
}

extern "C" void kernel_launch(void* const* d_in, const int* in_sizes, int n_in,
                              void* d_out, int out_size, void* d_ws, size_t ws_size,
                              hipStream_t stream) {
    const float* x   = (const float*)d_in[0];
    const int*   ei  = (const int*)d_in[1];
    const float* W1  = (const float*)d_in[3];
    const float* b1  = (const float*)d_in[4];
    const float* Wmu = (const float*)d_in[5];
    const float* bmu = (const float*)d_in[6];
    const float* Wls = (const float*)d_in[7];
    const float* bls = (const float*)d_in[8];

    const int N = in_sizes[0] / IN_DIM;
    const int E = in_sizes[1] / 2;
    const int* src = ei;
    const int* dst = ei + E;
    float* out = (float*)d_out;

    // workspace: dinv [N] | t [N*128] (t1 then t2) | Wcat [128*128]
    float* dinv = (float*)d_ws;
    float* t    = dinv + N;
    float* Wcat = t + (size_t)N * F1;
    // h (post-agg1 hidden, N*128 floats) lives in d_out (exact size match),
    // dead by the time agg2 overwrites d_out.
    float* h = out;

    k_build_wcat<<<cdiv_i(F1 * 2 * F2, 256), 256, 0, stream>>>(Wmu, Wls, Wcat);
    k_deg_init<<<cdiv_i(N, 256), 256, 0, stream>>>(dinv, N);
    k_deg_count<<<cdiv_i(E, 256), 256, 0, stream>>>(dst, dinv, E);
    k_dinv<<<cdiv_i(N, 256), 256, 0, stream>>>(dinv, N);

    // GEMM1: t = x @ W1   [N,256]@[256,128]
    k_gemm<<<dim3(cdiv_i(N, 64), F1 / 64), 256, 0, stream>>>(x, W1, t, N, IN_DIM, F1);

    // conv1 aggregation into h (=d_out), then ReLU
    k_agg_init_h<<<cdiv_i(N * F1, 256), 256, 0, stream>>>(t, dinv, b1, h, N);
    k_agg_edges128<<<cdiv_i(E * 32, 256), 256, 0, stream>>>(src, dst, dinv, t, h, E);
    k_relu<<<cdiv_i(N * F1, 256), 256, 0, stream>>>(h, N * F1);

    // GEMM2: t = h @ Wcat  [N,128]@[128,128]  (mu cols 0..63, ls cols 64..127)
    k_gemm<<<dim3(cdiv_i(N, 64), (2 * F2) / 64), 256, 0, stream>>>(h, Wcat, t, N, F1, 2 * F2);

    // conv2 aggregation directly into d_out (mu || logstd)
    k_agg_init_out<<<cdiv_i(N * F1, 256), 256, 0, stream>>>(t, dinv, bmu, bls, out, N);
    k_agg_edges_out<<<cdiv_i(E * 32, 256), 256, 0, stream>>>(src, dst, dinv, t, out, N, E);
}

// Round 3
// 637.859 us; speedup vs baseline: 8.9169x; 8.9169x over previous
//
#include <hip/hip_runtime.h>

// VGAE on GCN: N=50000, E=1.6M, IN=256, HIDDEN=128, OUT=64 (fp32).
// Round 3: fix k_gather2 logstd column index (was -F1, must be -F2) — R2's
// only defect; mu half + CSR + GEMMs verified correct by R2's partial pass.

#define IN_DIM 256
#define F1 128   // HIDDEN
#define F2 64    // OUT

static inline int cdiv_i(int a, int b) { return (a + b - 1) / b; }

// ---- Wcat = [W_mu | W_ls] : [128, 128] ----
__global__ void k_build_wcat(const float* __restrict__ Wmu, const float* __restrict__ Wls,
                             float* __restrict__ Wcat) {
    int i = blockIdx.x * blockDim.x + threadIdx.x;
    if (i >= F1 * 2 * F2) return;
    int k = i >> 7, c = i & 127;
    Wcat[i] = (c < F2) ? Wmu[k * F2 + c] : Wls[k * F2 + (c - F2)];
}

// ---- degree (int) ----
__global__ void k_zero_i(int* __restrict__ p, int n) {
    int i = blockIdx.x * blockDim.x + threadIdx.x;
    if (i < n) p[i] = 0;
}
__global__ void k_deg_count(const int* __restrict__ dst, int* __restrict__ deg, int E) {
    int e = blockIdx.x * blockDim.x + threadIdx.x;
    if (e < E) atomicAdd(&deg[dst[e]], 1);
}
__global__ void k_dinv(const int* __restrict__ deg, float* __restrict__ dinv, int N) {
    int i = blockIdx.x * blockDim.x + threadIdx.x;
    if (i < N) dinv[i] = rsqrtf((float)deg[i] + 1.0f);   // +1 self-loop
}

// ---- 3-phase exclusive scan of deg -> rowptr (N <= 65536: NB <= 256) ----
__global__ void k_scan_a(const int* __restrict__ deg, int* __restrict__ rowptr,
                         int* __restrict__ bsum, int N) {
    __shared__ int sd[256];
    int tid = threadIdx.x;
    int i = blockIdx.x * 256 + tid;
    int v = (i < N) ? deg[i] : 0;
    sd[tid] = v;
    __syncthreads();
    for (int ofs = 1; ofs < 256; ofs <<= 1) {
        int add = (tid >= ofs) ? sd[tid - ofs] : 0;
        __syncthreads();
        sd[tid] += add;
        __syncthreads();
    }
    if (i < N) rowptr[i] = sd[tid] - v;          // exclusive, no block base yet
    if (tid == 255) bsum[blockIdx.x] = sd[255];  // block total
}
__global__ void k_scan_b(int* __restrict__ bsum, int NB) {
    __shared__ int sd[256];
    int tid = threadIdx.x;
    int v = (tid < NB) ? bsum[tid] : 0;
    sd[tid] = v;
    __syncthreads();
    for (int ofs = 1; ofs < 256; ofs <<= 1) {
        int add = (tid >= ofs) ? sd[tid - ofs] : 0;
        __syncthreads();
        sd[tid] += add;
        __syncthreads();
    }
    if (tid < NB) bsum[tid] = sd[tid] - v;       // exclusive block bases
}
__global__ void k_scan_c(int* __restrict__ rowptr, int* __restrict__ cur,
                         const int* __restrict__ bsum, int N, int E) {
    int i = blockIdx.x * blockDim.x + threadIdx.x;
    if (i < N) {
        int r = rowptr[i] + bsum[i >> 8];
        rowptr[i] = r;
        cur[i] = r;
    }
    if (i == 0) rowptr[N] = E;
}

// ---- bucket scatter: edges sorted by dst ----
__global__ void k_scatter(const int* __restrict__ src, const int* __restrict__ dst,
                          int* __restrict__ cur, int* __restrict__ ssrc, int E) {
    int e = blockIdx.x * blockDim.x + threadIdx.x;
    if (e >= E) return;
    int pos = atomicAdd(&cur[dst[e]], 1);
    ssrc[pos] = src[e];
}

// ---- fp32 GEMM: C[M,N] = A[M,K] @ B[K,N]; BM=BN=64, BK=16, 256 thr, 4x4/thread ----
__global__ __launch_bounds__(256) void k_gemm(const float* __restrict__ A,
                                              const float* __restrict__ B,
                                              float* __restrict__ C,
                                              int M, int K, int N) {
    __shared__ float As[16][64];
    __shared__ float Bs[16][64];
    const int bm = blockIdx.x * 64;
    const int bn = blockIdx.y * 64;
    const int tid = threadIdx.x;
    const int tm = (tid >> 4) << 2;
    const int tn = (tid & 15) << 2;
    const int ar = tid >> 2;
    const int ac = (tid & 3) << 2;
    const int br = tid >> 4;
    const int bc = (tid & 15) << 2;

    float acc[4][4] = {{0.f}};

    for (int k0 = 0; k0 < K; k0 += 16) {
        float4 av = make_float4(0.f, 0.f, 0.f, 0.f);
        if (bm + ar < M) av = *(const float4*)(A + (size_t)(bm + ar) * K + k0 + ac);
        As[ac + 0][ar] = av.x; As[ac + 1][ar] = av.y;
        As[ac + 2][ar] = av.z; As[ac + 3][ar] = av.w;
        *(float4*)&Bs[br][bc] = *(const float4*)(B + (size_t)(k0 + br) * N + bn + bc);
        __syncthreads();
#pragma unroll
        for (int k = 0; k < 16; ++k) {
            float4 a = *(const float4*)&As[k][tm];
            float4 b = *(const float4*)&Bs[k][tn];
            acc[0][0] += a.x * b.x; acc[0][1] += a.x * b.y; acc[0][2] += a.x * b.z; acc[0][3] += a.x * b.w;
            acc[1][0] += a.y * b.x; acc[1][1] += a.y * b.y; acc[1][2] += a.y * b.z; acc[1][3] += a.y * b.w;
            acc[2][0] += a.z * b.x; acc[2][1] += a.z * b.y; acc[2][2] += a.z * b.z; acc[2][3] += a.z * b.w;
            acc[3][0] += a.w * b.x; acc[3][1] += a.w * b.y; acc[3][2] += a.w * b.z; acc[3][3] += a.w * b.w;
        }
        __syncthreads();
    }
#pragma unroll
    for (int i = 0; i < 4; ++i) {
        int gr = bm + tm + i;
        if (gr < M)
            *(float4*)(C + (size_t)gr * N + bn + tn) =
                make_float4(acc[i][0], acc[i][1], acc[i][2], acc[i][3]);
    }
}

// ---- conv1 gather: wave per node, lane owns feats {2*lane, 2*lane+1} ----
// h[n] = relu( t[n]*dinv[n]^2 + sum_e t[ssrc]*dinv[ssrc]*dinv[n] + b1 )
__global__ __launch_bounds__(256) void k_gather1(const int* __restrict__ rowptr,
                                                 const int* __restrict__ ssrc,
                                                 const float* __restrict__ dinv,
                                                 const float* __restrict__ t,
                                                 const float* __restrict__ b1,
                                                 float* __restrict__ h, int N) {
    int node = (blockIdx.x * blockDim.x + threadIdx.x) >> 6;
    int lane = threadIdx.x & 63;
    if (node >= N) return;
    float di = dinv[node];
    float2 acc = *(const float2*)(t + (size_t)node * F1 + (lane << 1));
    acc.x *= di * di; acc.y *= di * di;
    int e = rowptr[node], end = rowptr[node + 1];
    for (; e + 3 < end; e += 4) {
        int s0 = ssrc[e], s1 = ssrc[e + 1], s2 = ssrc[e + 2], s3 = ssrc[e + 3];
        float w0 = dinv[s0] * di, w1 = dinv[s1] * di, w2 = dinv[s2] * di, w3 = dinv[s3] * di;
        float2 v0 = *(const float2*)(t + (size_t)s0 * F1 + (lane << 1));
        float2 v1 = *(const float2*)(t + (size_t)s1 * F1 + (lane << 1));
        float2 v2 = *(const float2*)(t + (size_t)s2 * F1 + (lane << 1));
        float2 v3 = *(const float2*)(t + (size_t)s3 * F1 + (lane << 1));
        acc.x += v0.x * w0 + v1.x * w1 + v2.x * w2 + v3.x * w3;
        acc.y += v0.y * w0 + v1.y * w1 + v2.y * w2 + v3.y * w3;
    }
    for (; e < end; ++e) {
        int s = ssrc[e];
        float w = dinv[s] * di;
        float2 v = *(const float2*)(t + (size_t)s * F1 + (lane << 1));
        acc.x += v.x * w; acc.y += v.y * w;
    }
    float2 b = *(const float2*)(b1 + (lane << 1));
    *(float2*)(h + (size_t)node * F1 + (lane << 1)) =
        make_float2(fmaxf(acc.x + b.x, 0.f), fmaxf(acc.y + b.y, 0.f));
}

// ---- conv2 gather: same but split write into mu (cols 0..63) / logstd (64..127) ----
__global__ __launch_bounds__(256) void k_gather2(const int* __restrict__ rowptr,
                                                 const int* __restrict__ ssrc,
                                                 const float* __restrict__ dinv,
                                                 const float* __restrict__ t,
                                                 const float* __restrict__ bmu,
                                                 const float* __restrict__ bls,
                                                 float* __restrict__ out, int N) {
    int node = (blockIdx.x * blockDim.x + threadIdx.x) >> 6;
    int lane = threadIdx.x & 63;
    if (node >= N) return;
    float di = dinv[node];
    float2 acc = *(const float2*)(t + (size_t)node * F1 + (lane << 1));
    acc.x *= di * di; acc.y *= di * di;
    int e = rowptr[node], end = rowptr[node + 1];
    for (; e + 3 < end; e += 4) {
        int s0 = ssrc[e], s1 = ssrc[e + 1], s2 = ssrc[e + 2], s3 = ssrc[e + 3];
        float w0 = dinv[s0] * di, w1 = dinv[s1] * di, w2 = dinv[s2] * di, w3 = dinv[s3] * di;
        float2 v0 = *(const float2*)(t + (size_t)s0 * F1 + (lane << 1));
        float2 v1 = *(const float2*)(t + (size_t)s1 * F1 + (lane << 1));
        float2 v2 = *(const float2*)(t + (size_t)s2 * F1 + (lane << 1));
        float2 v3 = *(const float2*)(t + (size_t)s3 * F1 + (lane << 1));
        acc.x += v0.x * w0 + v1.x * w1 + v2.x * w2 + v3.x * w3;
        acc.y += v0.y * w0 + v1.y * w1 + v2.y * w2 + v3.y * w3;
    }
    for (; e < end; ++e) {
        int s = ssrc[e];
        float w = dinv[s] * di;
        float2 v = *(const float2*)(t + (size_t)s * F1 + (lane << 1));
        acc.x += v.x * w; acc.y += v.y * w;
    }
    if (lane < 32) {  // mu: cols 2*lane, 2*lane+1
        float2 b = *(const float2*)(bmu + (lane << 1));
        *(float2*)(out + (size_t)node * F2 + (lane << 1)) =
            make_float2(acc.x + b.x, acc.y + b.y);
    } else {          // logstd: feature f = 2*lane in [64,126] -> col f - 64
        int c = (lane << 1) - F2;
        float2 b = *(const float2*)(bls + c);
        *(float2*)(out + (size_t)N * F2 + (size_t)node * F2 + c) =
            make_float2(acc.x + b.x, acc.y + b.y);
    }
}

extern "C" void kernel_launch(void* const* d_in, const int* in_sizes, int n_in,
                              void* d_out, int out_size, void* d_ws, size_t ws_size,
                              hipStream_t stream) {
    const float* x   = (const float*)d_in[0];
    const int*   ei  = (const int*)d_in[1];
    const float* W1  = (const float*)d_in[3];
    const float* b1  = (const float*)d_in[4];
    const float* Wmu = (const float*)d_in[5];
    const float* bmu = (const float*)d_in[6];
    const float* Wls = (const float*)d_in[7];
    const float* bls = (const float*)d_in[8];

    const int N = in_sizes[0] / IN_DIM;
    const int E = in_sizes[1] / 2;
    const int* src = ei;
    const int* dst = ei + E;
    float* out = (float*)d_out;

    // ---- workspace carve (4B elems, 16B-aligned regions) ----
    size_t off = 0;
    auto carve = [&](size_t n) { size_t o = off; off += (n + 3) & ~(size_t)3; return o; };
    float* ws = (float*)d_ws;
    int*   deg    = (int*)(ws + carve(N));
    float* dinv   =        ws + carve(N);
    int*   rowptr = (int*)(ws + carve(N + 1));
    int*   cur    = (int*)(ws + carve(N));
    int*   bsum   = (int*)(ws + carve(256));
    int*   ssrc   = (int*)(ws + carve(E));
    float* t      =        ws + carve((size_t)N * F1);
    float* Wcat   =        ws + carve(F1 * 2 * F2);
    (void)ws_size;
    // h (post-agg1 hidden, N*128 floats) lives in d_out; dead before agg2 writes.
    float* h = out;

    const int NB = cdiv_i(N, 256);  // 196 <= 256

    k_build_wcat<<<cdiv_i(F1 * 2 * F2, 256), 256, 0, stream>>>(Wmu, Wls, Wcat);

    // CSR build
    k_zero_i<<<cdiv_i(N, 256), 256, 0, stream>>>(deg, N);
    k_deg_count<<<cdiv_i(E, 256), 256, 0, stream>>>(dst, deg, E);
    k_dinv<<<cdiv_i(N, 256), 256, 0, stream>>>(deg, dinv, N);
    k_scan_a<<<NB, 256, 0, stream>>>(deg, rowptr, bsum, N);
    k_scan_b<<<1, 256, 0, stream>>>(bsum, NB);
    k_scan_c<<<NB, 256, 0, stream>>>(rowptr, cur, bsum, N, E);
    k_scatter<<<cdiv_i(E, 256), 256, 0, stream>>>(src, dst, cur, ssrc, E);

    // GEMM1: t = x @ W1   [N,256]@[256,128]
    k_gemm<<<dim3(cdiv_i(N, 64), F1 / 64), 256, 0, stream>>>(x, W1, t, N, IN_DIM, F1);
    // conv1 aggregate (gather) + bias + relu -> h (in d_out)
    k_gather1<<<cdiv_i(N * 64, 256), 256, 0, stream>>>(rowptr, ssrc, dinv, t, b1, h, N);

    // GEMM2: t = h @ Wcat  [N,128]@[128,128]
    k_gemm<<<dim3(cdiv_i(N, 64), (2 * F2) / 64), 256, 0, stream>>>(h, Wcat, t, N, F1, 2 * F2);
    // conv2 aggregate (gather) -> out (mu || logstd)
    k_gather2<<<cdiv_i(N * 64, 256), 256, 0, stream>>>(rowptr, ssrc, dinv, t, bmu, bls, out, N);
}